// Round 7
// baseline (528.334 us; speedup 1.0000x reference)
//
#include <hip/hip_runtime.h>
#include <hip/hip_bf16.h>

typedef __attribute__((ext_vector_type(8))) short short8;   // 8 bf16 = 4 VGPR (guide §3)
typedef __attribute__((ext_vector_type(4))) float f32x4;

#define S_DIM 512
#define T_DIM 128
#define D_DIM 256
#define HD 64
#define NROWS 65536
static constexpr float LN_EPS = 1e-5f;

static __device__ __forceinline__ ushort f2bf(float f) {
    uint32_t b = __float_as_uint(f);
    b += 0x7FFF + ((b >> 16) & 1);   // RNE
    return (ushort)(b >> 16);
}

// ---------------------------------------------------------------------------
// LayerNorm fp32 -> bf16. One wave per 256-row; 4 rows per block.
// ---------------------------------------------------------------------------
__global__ __launch_bounds__(256) void ln_bf16(const float* __restrict__ x,
                                               const float* __restrict__ g,
                                               const float* __restrict__ b,
                                               ushort* __restrict__ out) {
    int row = blockIdx.x * 4 + (threadIdx.x >> 6);
    int lane = threadIdx.x & 63;
    size_t base = (size_t)row * D_DIM + lane * 4;
    float4 xv = *reinterpret_cast<const float4*>(x + base);
    float s = xv.x + xv.y + xv.z + xv.w;
    float q = xv.x * xv.x + xv.y * xv.y + xv.z * xv.z + xv.w * xv.w;
#pragma unroll
    for (int off = 32; off > 0; off >>= 1) {
        s += __shfl_xor(s, off);
        q += __shfl_xor(q, off);
    }
    float mu = s * (1.0f / D_DIM);
    float var = q * (1.0f / D_DIM) - mu * mu;
    float rstd = rsqrtf(var + LN_EPS);
    float4 gv = *reinterpret_cast<const float4*>(g + lane * 4);
    float4 bv = *reinterpret_cast<const float4*>(b + lane * 4);
    ushort4 o = make_ushort4(f2bf((xv.x - mu) * rstd * gv.x + bv.x),
                             f2bf((xv.y - mu) * rstd * gv.y + bv.y),
                             f2bf((xv.z - mu) * rstd * gv.z + bv.z),
                             f2bf((xv.w - mu) * rstd * gv.w + bv.w));
    *reinterpret_cast<ushort4*>(out + base) = o;
}

// ---------------------------------------------------------------------------
// Weight conversion fp32 -> bf16 (5 x 256x256)
// ---------------------------------------------------------------------------
__global__ __launch_bounds__(256) void wconv(const float* __restrict__ w0, const float* __restrict__ w1,
                                             const float* __restrict__ w2, const float* __restrict__ w3,
                                             const float* __restrict__ w4, ushort* __restrict__ dst) {
    const float* s;
    switch (blockIdx.y) {
        case 0: s = w0; break;
        case 1: s = w1; break;
        case 2: s = w2; break;
        case 3: s = w3; break;
        default: s = w4; break;
    }
    int idx = (blockIdx.x * 256 + threadIdx.x) * 4;
    float4 v = *reinterpret_cast<const float4*>(s + idx);
    ushort4 o = make_ushort4(f2bf(v.x), f2bf(v.y), f2bf(v.z), f2bf(v.w));
    *reinterpret_cast<ushort4*>(dst + (size_t)blockIdx.y * 65536 + idx) = o;
}

// ---------------------------------------------------------------------------
// bf16 MFMA GEMM: C[m][n] = sum_k A[m][k] * W[n][k]  (W row-major [N][K])
// BM=BN=128, BK=64, 256 thr (4 waves, each 64x64 out).
// LDS tiles XOR-swizzled (chunk ^= row&7) on both write and read sides.
// OUT_QK / OUT_VT use t-major row blocking (block = fixed t, 128 consecutive
// s) so the [T,S,D] / [T,D,S] outputs are written with good locality.
// ---------------------------------------------------------------------------
enum { OUT_QK = 0, OUT_VT = 1, OUT_H = 2, OUT_FFN2 = 3 };

template <int MODE>
__global__ __launch_bounds__(256) void gemm_bf16(const ushort* __restrict__ A,
                                                 const ushort* __restrict__ W,
                                                 const float* __restrict__ bias,
                                                 const float* __restrict__ res,
                                                 void* __restrict__ outp) {
    __shared__ uint4 As[1024];   // 128 rows x 8 chunks of 16B
    __shared__ uint4 Bs[1024];
    const int tid = threadIdx.x;
    const int lane = tid & 63;
    const int wid = tid >> 6;
    const int m0 = blockIdx.x * 128;
    const int n0 = blockIdx.y * 128;
    const int wm = (wid >> 1) * 64;
    const int wn = (wid & 1) * 64;

    constexpr bool TMAJ = (MODE == OUT_VT || MODE == OUT_QK);
    // t-major modes: virtual row order r' = t*S + s (t fixed per block)
    const int tblk = m0 >> 9;        // m0 / S_DIM
    const int s0 = m0 & (S_DIM - 1);

    f32x4 acc[4][4];
#pragma unroll
    for (int mi = 0; mi < 4; ++mi)
#pragma unroll
        for (int ni = 0; ni < 4; ++ni) acc[mi][ni] = (f32x4){0.f, 0.f, 0.f, 0.f};

    const ushort* Abase = TMAJ ? A + ((size_t)s0 * T_DIM + tblk) * D_DIM
                               : A + (size_t)m0 * D_DIM;
    const size_t Astride = TMAJ ? (size_t)T_DIM * D_DIM : (size_t)D_DIM;
    const ushort* Wbase = W + (size_t)n0 * D_DIM;
    uint4 ra[4], rb[4];

#define GLOAD(dstreg, base, stride, k0)                                                     \
    {                                                                                       \
        _Pragma("unroll") for (int it = 0; it < 4; ++it) {                                  \
            int L = it * 256 + tid;                                                         \
            int row = L >> 3, c = L & 7;                                                    \
            dstreg[it] = *reinterpret_cast<const uint4*>(base + (size_t)row * (stride) + (k0) + c * 8); \
        }                                                                                   \
    }
#define SWRITE(lds, srcreg)                                                                 \
    {                                                                                       \
        _Pragma("unroll") for (int it = 0; it < 4; ++it) {                                  \
            int L = it * 256 + tid;                                                         \
            int row = L >> 3, c = L & 7;                                                    \
            lds[row * 8 + (c ^ (row & 7))] = srcreg[it];                                    \
        }                                                                                   \
    }

    GLOAD(ra, Abase, Astride, 0)
    GLOAD(rb, Wbase, D_DIM, 0)
    for (int ks = 0; ks < 4; ++ks) {
        __syncthreads();
        SWRITE(As, ra)
        SWRITE(Bs, rb)
        __syncthreads();
        if (ks < 3) {
            GLOAD(ra, Abase, Astride, (ks + 1) * 64)
            GLOAD(rb, Wbase, D_DIM, (ks + 1) * 64)
        }
#pragma unroll
        for (int kk = 0; kk < 2; ++kk) {
            short8 af[4], bf[4];
#pragma unroll
            for (int mi = 0; mi < 4; ++mi) {
                int row = wm + mi * 16 + (lane & 15);
                int c = kk * 4 + (lane >> 4);
                af[mi] = *reinterpret_cast<const short8*>(&As[row * 8 + (c ^ (lane & 7))]);
            }
#pragma unroll
            for (int ni = 0; ni < 4; ++ni) {
                int row = wn + ni * 16 + (lane & 15);
                int c = kk * 4 + (lane >> 4);
                bf[ni] = *reinterpret_cast<const short8*>(&Bs[row * 8 + (c ^ (lane & 7))]);
            }
#pragma unroll
            for (int mi = 0; mi < 4; ++mi)
#pragma unroll
                for (int ni = 0; ni < 4; ++ni)
                    acc[mi][ni] = __builtin_amdgcn_mfma_f32_16x16x32_bf16(af[mi], bf[ni], acc[mi][ni], 0, 0, 0);
        }
    }

    // Epilogue. D layout: row=(lane>>4)*4+r, col=lane&15 (m89).
#pragma unroll
    for (int mi = 0; mi < 4; ++mi) {
#pragma unroll
        for (int ni = 0; ni < 4; ++ni) {
            int gn = n0 + wn + ni * 16 + (lane & 15);
            if (MODE == OUT_VT) {
                // 4 accum rows = 4 consecutive s at fixed (t, gn) -> ushort4
                int s = s0 + wm + mi * 16 + (lane >> 4) * 4;
                ushort4 o = make_ushort4(f2bf(acc[mi][ni][0]), f2bf(acc[mi][ni][1]),
                                         f2bf(acc[mi][ni][2]), f2bf(acc[mi][ni][3]));
                *reinterpret_cast<ushort4*>(
                    &((ushort*)outp)[((size_t)tblk * D_DIM + gn) * S_DIM + s]) = o;
            } else if (MODE == OUT_QK) {
#pragma unroll
                for (int r = 0; r < 4; ++r) {
                    int s = s0 + wm + mi * 16 + (lane >> 4) * 4 + r;
                    ((ushort*)outp)[(size_t)tblk * (S_DIM * D_DIM) + (size_t)s * D_DIM + gn] =
                        f2bf(acc[mi][ni][r]);
                }
            } else {
#pragma unroll
                for (int r = 0; r < 4; ++r) {
                    int gm = m0 + wm + mi * 16 + (lane >> 4) * 4 + r;
                    float v = acc[mi][ni][r];
                    if (MODE == OUT_H) {
                        v += bias[gn];
                        v = fmaxf(v, 0.f);
                        ((ushort*)outp)[(size_t)gm * D_DIM + gn] = f2bf(v);
                    } else {
                        v += bias[gn] + res[(size_t)gm * D_DIM + gn];
                        ((float*)outp)[(size_t)gm * D_DIM + gn] = v;
                    }
                }
            }
        }
    }
#undef GLOAD
#undef SWRITE
}

// ---------------------------------------------------------------------------
// MFMA flash attention. Block = 4 waves, each wave owns 16 q-rows of one (t,h).
// Grid (i-chunk, h, t) — round-5 ordering: h-partners of an xt row share an
// XCD (id ≡ i mod 8) so 256B h-quarters merge into full-line writebacks.
// K [T,S,D] / V^T [T,D,S] tiles double-buffered in LDS (reg-staged prefetch).
// No online max (scores/temp ~ N(0,1)); deferred row-sum normalization.
// ---------------------------------------------------------------------------
__global__ __launch_bounds__(256) void attn_mfma(const ushort* __restrict__ qb,
                                                 const ushort* __restrict__ kb,
                                                 const ushort* __restrict__ vtb,
                                                 const float* __restrict__ x,
                                                 float* __restrict__ xt) {
    __shared__ uint4 Ks[2][512];   // 64 rows x 8 chunks, double-buffered
    __shared__ uint4 Vs[2][512];
    __shared__ uint4 Ps[512];      // 4 waves x (16 rows x 8 chunks)
    const int tid = threadIdx.x;
    const int lane = tid & 63;
    const int wid = tid >> 6;
    const int h = blockIdx.y, t = blockIdx.z;
    const int i0 = blockIdx.x * 64 + wid * 16;

    short8 qf[2];
    {
        const ushort* qrow = qb + ((size_t)t * S_DIM + i0 + (lane & 15)) * D_DIM + h * HD;
#pragma unroll
        for (int kk = 0; kk < 2; ++kk)
            qf[kk] = *reinterpret_cast<const short8*>(qrow + kk * 32 + (lane >> 4) * 8);
    }

    f32x4 oacc[4];
    float ps[4];
#pragma unroll
    for (int dt = 0; dt < 4; ++dt) oacc[dt] = (f32x4){0.f, 0.f, 0.f, 0.f};
#pragma unroll
    for (int r = 0; r < 4; ++r) ps[r] = 0.f;

    const ushort* kbase = kb + (size_t)t * (S_DIM * D_DIM) + h * HD;
    const ushort* vbase = vtb + ((size_t)t * D_DIM + h * HD) * S_DIM;
    ushort* psw = (ushort*)&Ps[wid * 128];
    uint4 rk[2], rv[2];

#define LOADKV(j0)                                                                     \
    {                                                                                  \
        _Pragma("unroll") for (int it = 0; it < 2; ++it) {                             \
            int L = it * 256 + tid;                                                    \
            int row = L >> 3, c = L & 7;                                               \
            rk[it] = *reinterpret_cast<const uint4*>(kbase + (size_t)((j0) + row) * D_DIM + c * 8); \
            rv[it] = *reinterpret_cast<const uint4*>(vbase + (size_t)row * S_DIM + (j0) + c * 8);   \
        }                                                                              \
    }
#define WRITEKV(buf)                                                                   \
    {                                                                                  \
        _Pragma("unroll") for (int it = 0; it < 2; ++it) {                             \
            int L = it * 256 + tid;                                                    \
            int row = L >> 3, c = L & 7;                                               \
            Ks[buf][row * 8 + (c ^ (row & 7))] = rk[it];                               \
            Vs[buf][row * 8 + (c ^ (row & 7))] = rv[it];                               \
        }                                                                              \
    }

    LOADKV(0)
    WRITEKV(0)
    __syncthreads();
    int cur = 0;

    for (int jt = 0; jt < 8; ++jt) {
        if (jt < 7) LOADKV((jt + 1) * 64)   // prefetch next tile into regs

        // S = Q K^T : mfma(Q-frag, K-frag) -> D[i][j], i=(lane>>4)*4+r, j=lane&15 (+16ct)
        f32x4 sacc[4];
#pragma unroll
        for (int ct = 0; ct < 4; ++ct) sacc[ct] = (f32x4){0.f, 0.f, 0.f, 0.f};
#pragma unroll
        for (int kk = 0; kk < 2; ++kk) {
#pragma unroll
            for (int ct = 0; ct < 4; ++ct) {
                int row = ct * 16 + (lane & 15);
                int c = kk * 4 + (lane >> 4);
                short8 kf = *reinterpret_cast<const short8*>(&Ks[cur][row * 8 + (c ^ (lane & 7))]);
                sacc[ct] = __builtin_amdgcn_mfma_f32_16x16x32_bf16(qf[kk], kf, sacc[ct], 0, 0, 0);
            }
        }
        // P = exp(S/temp); accumulate per-lane partial row sums; stash bf16 P in
        // swizzled per-wave LDS for the transpose to A-fragment layout.
#pragma unroll
        for (int ct = 0; ct < 4; ++ct) {
#pragma unroll
            for (int r = 0; r < 4; ++r) {
                float p = __expf(sacc[ct][r] * 0.125f);
                ps[r] += p;
                int i = (lane >> 4) * 4 + r;
                int j = (lane & 15) + 16 * ct;
                psw[i * 64 + (j ^ ((i & 7) << 3))] = f2bf(p);
            }
        }
        // O += P V : mfma(P-frag, Vt-frag)
#pragma unroll
        for (int jh = 0; jh < 2; ++jh) {
            int c = jh * 4 + (lane >> 4);
            short8 pf = *reinterpret_cast<const short8*>(&Ps[wid * 128 + (lane & 15) * 8 + (c ^ (lane & 7))]);
#pragma unroll
            for (int dt = 0; dt < 4; ++dt) {
                int row = dt * 16 + (lane & 15);
                short8 vf = *reinterpret_cast<const short8*>(&Vs[cur][row * 8 + (c ^ (lane & 7))]);
                oacc[dt] = __builtin_amdgcn_mfma_f32_16x16x32_bf16(pf, vf, oacc[dt], 0, 0, 0);
            }
        }

        if (jt < 7) {
            __syncthreads();      // all waves done reading buf cur^1 (last read jt-1)
            WRITEKV(cur ^ 1)
            __syncthreads();      // new tile visible to all waves
            cur ^= 1;
        }
    }
#undef LOADKV
#undef WRITEKV

    // Full row sums (16-lane butterfly, once per kernel) and normalize.
#pragma unroll
    for (int r = 0; r < 4; ++r) {
#pragma unroll
        for (int off = 1; off < 16; off <<= 1) ps[r] += __shfl_xor(ps[r], off);
        ps[r] = 1.0f / ps[r];
    }
#pragma unroll
    for (int dt = 0; dt < 4; ++dt) {
#pragma unroll
        for (int r = 0; r < 4; ++r) {
            int srow = i0 + (lane >> 4) * 4 + r;
            size_t oidx = (size_t)srow * (T_DIM * D_DIM) + (size_t)t * D_DIM + h * HD + dt * 16 + (lane & 15);
            xt[oidx] = x[oidx] + oacc[dt][r] * ps[r];
        }
    }
}

// ---------------------------------------------------------------------------
extern "C" void kernel_launch(void* const* d_in, const int* in_sizes, int n_in,
                              void* d_out, int out_size, void* d_ws, size_t ws_size,
                              hipStream_t stream) {
    const float* x  = (const float*)d_in[0];
    const float* wq = (const float*)d_in[1];
    const float* wk = (const float*)d_in[2];
    const float* wv = (const float*)d_in[3];
    const float* g1 = (const float*)d_in[4];
    const float* be1 = (const float*)d_in[5];
    const float* g2 = (const float*)d_in[6];
    const float* be2 = (const float*)d_in[7];
    const float* w1 = (const float*)d_in[8];
    const float* b1 = (const float*)d_in[9];
    const float* w2 = (const float*)d_in[10];
    const float* b2 = (const float*)d_in[11];
    float* out = (float*)d_out;

    char* ws = (char*)d_ws;
    const size_t MB = 1024ull * 1024;
    ushort* xnb = (ushort*)ws;                // 32 MB: LN1 out, later LN2 out
    ushort* qb  = (ushort*)(ws + 32 * MB);    // 32 MB: Q [T,S,D]; later FFN hidden
    ushort* kb  = (ushort*)(ws + 64 * MB);    // 32 MB: K [T,S,D]
    ushort* vtb = (ushort*)(ws + 96 * MB);    // 32 MB: V^T [T,D,S]
    ushort* wb  = (ushort*)(ws + 128 * MB);   // 5 x 64K bf16 weights
    ushort* wqb = wb;
    ushort* wkb = wb + 65536;
    ushort* wvb = wb + 2 * 65536;
    ushort* w1b = wb + 3 * 65536;
    ushort* w2b = wb + 4 * 65536;
    ushort* hb  = qb;

    dim3 gg(NROWS / 128, D_DIM / 128);

    wconv<<<dim3(64, 5), 256, 0, stream>>>(wq, wk, wv, w1, w2, wb);
    ln_bf16<<<NROWS / 4, 256, 0, stream>>>(x, g1, be1, xnb);
    gemm_bf16<OUT_QK><<<gg, 256, 0, stream>>>(xnb, wqb, nullptr, nullptr, qb);
    gemm_bf16<OUT_QK><<<gg, 256, 0, stream>>>(xnb, wkb, nullptr, nullptr, kb);
    gemm_bf16<OUT_VT><<<gg, 256, 0, stream>>>(xnb, wvb, nullptr, nullptr, vtb);
    attn_mfma<<<dim3(S_DIM / 64, 4, T_DIM), 256, 0, stream>>>(qb, kb, vtb, x, out);
    ln_bf16<<<NROWS / 4, 256, 0, stream>>>(out, g2, be2, xnb);
    gemm_bf16<OUT_H><<<gg, 256, 0, stream>>>(xnb, w1b, b1, nullptr, hb);
    gemm_bf16<OUT_FFN2><<<gg, 256, 0, stream>>>(hb, w2b, b2, out, out);
}

// Round 8
// 404.608 us; speedup vs baseline: 1.3058x; 1.3058x over previous
//
#include <hip/hip_runtime.h>
#include <hip/hip_bf16.h>

typedef __attribute__((ext_vector_type(8))) short short8;   // 8 bf16 = 4 VGPR (guide §3)
typedef __attribute__((ext_vector_type(4))) float f32x4;

#define S_DIM 512
#define T_DIM 128
#define D_DIM 256
#define HD 64
#define NROWS 65536
static constexpr float LN_EPS = 1e-5f;

static __device__ __forceinline__ ushort f2bf(float f) {
    uint32_t b = __float_as_uint(f);
    b += 0x7FFF + ((b >> 16) & 1);   // RNE
    return (ushort)(b >> 16);
}

// ---------------------------------------------------------------------------
// LayerNorm fp32 -> bf16. One wave per 256-row; 4 rows per block.
// ---------------------------------------------------------------------------
__global__ __launch_bounds__(256) void ln_bf16(const float* __restrict__ x,
                                               const float* __restrict__ g,
                                               const float* __restrict__ b,
                                               ushort* __restrict__ out) {
    int row = blockIdx.x * 4 + (threadIdx.x >> 6);
    int lane = threadIdx.x & 63;
    size_t base = (size_t)row * D_DIM + lane * 4;
    float4 xv = *reinterpret_cast<const float4*>(x + base);
    float s = xv.x + xv.y + xv.z + xv.w;
    float q = xv.x * xv.x + xv.y * xv.y + xv.z * xv.z + xv.w * xv.w;
#pragma unroll
    for (int off = 32; off > 0; off >>= 1) {
        s += __shfl_xor(s, off);
        q += __shfl_xor(q, off);
    }
    float mu = s * (1.0f / D_DIM);
    float var = q * (1.0f / D_DIM) - mu * mu;
    float rstd = rsqrtf(var + LN_EPS);
    float4 gv = *reinterpret_cast<const float4*>(g + lane * 4);
    float4 bv = *reinterpret_cast<const float4*>(b + lane * 4);
    ushort4 o = make_ushort4(f2bf((xv.x - mu) * rstd * gv.x + bv.x),
                             f2bf((xv.y - mu) * rstd * gv.y + bv.y),
                             f2bf((xv.z - mu) * rstd * gv.z + bv.z),
                             f2bf((xv.w - mu) * rstd * gv.w + bv.w));
    *reinterpret_cast<ushort4*>(out + base) = o;
}

// ---------------------------------------------------------------------------
// Weight conversion fp32 -> bf16 (5 x 256x256)
// ---------------------------------------------------------------------------
__global__ __launch_bounds__(256) void wconv(const float* __restrict__ w0, const float* __restrict__ w1,
                                             const float* __restrict__ w2, const float* __restrict__ w3,
                                             const float* __restrict__ w4, ushort* __restrict__ dst) {
    const float* s;
    switch (blockIdx.y) {
        case 0: s = w0; break;
        case 1: s = w1; break;
        case 2: s = w2; break;
        case 3: s = w3; break;
        default: s = w4; break;
    }
    int idx = (blockIdx.x * 256 + threadIdx.x) * 4;
    float4 v = *reinterpret_cast<const float4*>(s + idx);
    ushort4 o = make_ushort4(f2bf(v.x), f2bf(v.y), f2bf(v.z), f2bf(v.w));
    *reinterpret_cast<ushort4*>(dst + (size_t)blockIdx.y * 65536 + idx) = o;
}

// ---------------------------------------------------------------------------
// bf16 MFMA GEMM: C[m][n] = sum_k A[m][k] * W[n][k]  (W row-major [N][K])
// BM=BN=128, BK=64, 256 thr (4 waves, each 64x64 out).
// LDS tiles XOR-swizzled (chunk ^= row&7) on both write and read sides.
// OUT_QK / OUT_VT use t-major row blocking (block = fixed t, 128 consecutive
// s) so the [T,S,D] / [T,D,S] outputs are written with good locality.
// ---------------------------------------------------------------------------
enum { OUT_QK = 0, OUT_VT = 1, OUT_H = 2, OUT_FFN2 = 3 };

template <int MODE>
__global__ __launch_bounds__(256) void gemm_bf16(const ushort* __restrict__ A,
                                                 const ushort* __restrict__ W,
                                                 const float* __restrict__ bias,
                                                 const float* __restrict__ res,
                                                 void* __restrict__ outp) {
    __shared__ uint4 As[1024];   // 128 rows x 8 chunks of 16B
    __shared__ uint4 Bs[1024];
    const int tid = threadIdx.x;
    const int lane = tid & 63;
    const int wid = tid >> 6;
    const int m0 = blockIdx.x * 128;
    const int n0 = blockIdx.y * 128;
    const int wm = (wid >> 1) * 64;
    const int wn = (wid & 1) * 64;

    constexpr bool TMAJ = (MODE == OUT_VT || MODE == OUT_QK);
    // t-major modes: virtual row order r' = t*S + s (t fixed per block)
    const int tblk = m0 >> 9;        // m0 / S_DIM
    const int s0 = m0 & (S_DIM - 1);

    f32x4 acc[4][4];
#pragma unroll
    for (int mi = 0; mi < 4; ++mi)
#pragma unroll
        for (int ni = 0; ni < 4; ++ni) acc[mi][ni] = (f32x4){0.f, 0.f, 0.f, 0.f};

    const ushort* Abase = TMAJ ? A + ((size_t)s0 * T_DIM + tblk) * D_DIM
                               : A + (size_t)m0 * D_DIM;
    const size_t Astride = TMAJ ? (size_t)T_DIM * D_DIM : (size_t)D_DIM;
    const ushort* Wbase = W + (size_t)n0 * D_DIM;
    uint4 ra[4], rb[4];

#define GLOAD(dstreg, base, stride, k0)                                                     \
    {                                                                                       \
        _Pragma("unroll") for (int it = 0; it < 4; ++it) {                                  \
            int L = it * 256 + tid;                                                         \
            int row = L >> 3, c = L & 7;                                                    \
            dstreg[it] = *reinterpret_cast<const uint4*>(base + (size_t)row * (stride) + (k0) + c * 8); \
        }                                                                                   \
    }
#define SWRITE(lds, srcreg)                                                                 \
    {                                                                                       \
        _Pragma("unroll") for (int it = 0; it < 4; ++it) {                                  \
            int L = it * 256 + tid;                                                         \
            int row = L >> 3, c = L & 7;                                                    \
            lds[row * 8 + (c ^ (row & 7))] = srcreg[it];                                    \
        }                                                                                   \
    }

    GLOAD(ra, Abase, Astride, 0)
    GLOAD(rb, Wbase, D_DIM, 0)
    for (int ks = 0; ks < 4; ++ks) {
        __syncthreads();
        SWRITE(As, ra)
        SWRITE(Bs, rb)
        __syncthreads();
        if (ks < 3) {
            GLOAD(ra, Abase, Astride, (ks + 1) * 64)
            GLOAD(rb, Wbase, D_DIM, (ks + 1) * 64)
        }
#pragma unroll
        for (int kk = 0; kk < 2; ++kk) {
            short8 af[4], bf[4];
#pragma unroll
            for (int mi = 0; mi < 4; ++mi) {
                int row = wm + mi * 16 + (lane & 15);
                int c = kk * 4 + (lane >> 4);
                af[mi] = *reinterpret_cast<const short8*>(&As[row * 8 + (c ^ (lane & 7))]);
            }
#pragma unroll
            for (int ni = 0; ni < 4; ++ni) {
                int row = wn + ni * 16 + (lane & 15);
                int c = kk * 4 + (lane >> 4);
                bf[ni] = *reinterpret_cast<const short8*>(&Bs[row * 8 + (c ^ (lane & 7))]);
            }
#pragma unroll
            for (int mi = 0; mi < 4; ++mi)
#pragma unroll
                for (int ni = 0; ni < 4; ++ni)
                    acc[mi][ni] = __builtin_amdgcn_mfma_f32_16x16x32_bf16(af[mi], bf[ni], acc[mi][ni], 0, 0, 0);
        }
    }

    // Epilogue. D layout: row=(lane>>4)*4+r, col=lane&15 (m89).
#pragma unroll
    for (int mi = 0; mi < 4; ++mi) {
#pragma unroll
        for (int ni = 0; ni < 4; ++ni) {
            int gn = n0 + wn + ni * 16 + (lane & 15);
            if (MODE == OUT_VT) {
                // 4 accum rows = 4 consecutive s at fixed (t, gn) -> ushort4
                int s = s0 + wm + mi * 16 + (lane >> 4) * 4;
                ushort4 o = make_ushort4(f2bf(acc[mi][ni][0]), f2bf(acc[mi][ni][1]),
                                         f2bf(acc[mi][ni][2]), f2bf(acc[mi][ni][3]));
                *reinterpret_cast<ushort4*>(
                    &((ushort*)outp)[((size_t)tblk * D_DIM + gn) * S_DIM + s]) = o;
            } else if (MODE == OUT_QK) {
#pragma unroll
                for (int r = 0; r < 4; ++r) {
                    int s = s0 + wm + mi * 16 + (lane >> 4) * 4 + r;
                    ((ushort*)outp)[(size_t)tblk * (S_DIM * D_DIM) + (size_t)s * D_DIM + gn] =
                        f2bf(acc[mi][ni][r]);
                }
            } else {
#pragma unroll
                for (int r = 0; r < 4; ++r) {
                    int gm = m0 + wm + mi * 16 + (lane >> 4) * 4 + r;
                    float v = acc[mi][ni][r];
                    if (MODE == OUT_H) {
                        v += bias[gn];
                        v = fmaxf(v, 0.f);
                        ((ushort*)outp)[(size_t)gm * D_DIM + gn] = f2bf(v);
                    } else {
                        v += bias[gn] + res[(size_t)gm * D_DIM + gn];
                        ((float*)outp)[(size_t)gm * D_DIM + gn] = v;
                    }
                }
            }
        }
    }
#undef GLOAD
#undef SWRITE
}

// ---------------------------------------------------------------------------
// MFMA flash attention. Block = 4 waves, each wave owns 16 q-rows of one (t,h).
// Grid (i-chunk, h, t) — round-5 ordering (h-partners of an xt row share an
// XCD so 256B h-quarters merge into full-line writebacks).
// K/V double-buffered via __builtin_amdgcn_global_load_lds (width 16): LDS
// dest is linear (lane*16 within wave-uniform base), the XOR swizzle is
// applied to the per-lane GLOBAL source chunk (rule #21), read side unchanged.
// No per-thread staging registers -> no spill (round 6/7 write-amp mechanism).
// One __syncthreads per tile drains vmcnt (m97 pattern).
// ---------------------------------------------------------------------------
__global__ __launch_bounds__(256) void attn_mfma(const ushort* __restrict__ qb,
                                                 const ushort* __restrict__ kb,
                                                 const ushort* __restrict__ vtb,
                                                 const float* __restrict__ x,
                                                 float* __restrict__ xt) {
    __shared__ uint4 Ks[2][512];   // 64 rows x 8 chunks, double-buffered
    __shared__ uint4 Vs[2][512];
    __shared__ uint4 Ps[512];      // 4 waves x (16 rows x 8 chunks)
    const int tid = threadIdx.x;
    const int lane = tid & 63;
    const int wid = tid >> 6;
    const int h = blockIdx.y, t = blockIdx.z;
    const int i0 = blockIdx.x * 64 + wid * 16;

    short8 qf[2];
    {
        const ushort* qrow = qb + ((size_t)t * S_DIM + i0 + (lane & 15)) * D_DIM + h * HD;
#pragma unroll
        for (int kk = 0; kk < 2; ++kk)
            qf[kk] = *reinterpret_cast<const short8*>(qrow + kk * 32 + (lane >> 4) * 8);
    }

    f32x4 oacc[4];
    float ps[4];
#pragma unroll
    for (int dt = 0; dt < 4; ++dt) oacc[dt] = (f32x4){0.f, 0.f, 0.f, 0.f};
#pragma unroll
    for (int r = 0; r < 4; ++r) ps[r] = 0.f;

    const ushort* kbase = kb + (size_t)t * (S_DIM * D_DIM) + h * HD;
    const ushort* vbase = vtb + ((size_t)t * D_DIM + h * HD) * S_DIM;
    ushort* psw = (ushort*)&Ps[wid * 128];

    // Async stage of one 64x64 K tile + V tile into LDS buffer `buf`.
    // Wave w fills LDS slots [w*128, w*128+128) with 2 gload_lds (64 lanes x 16B).
    // Lane's slot = w*128 + it*64 + lane; row = slot>>3; global chunk = (slot&7)^(row&7)
    // => LDS[row*8+c'] holds global chunk c'^(row&7), matching the swizzled reads.
#define STAGE(buf, j0)                                                                      \
    {                                                                                       \
        _Pragma("unroll") for (int it = 0; it < 2; ++it) {                                  \
            int slot = wid * 128 + it * 64 + lane;                                          \
            int row = slot >> 3;                                                            \
            int c = (slot & 7) ^ (row & 7);                                                 \
            __builtin_amdgcn_global_load_lds(                                               \
                (const __attribute__((address_space(1))) void*)(kbase + (size_t)((j0) + row) * D_DIM + c * 8), \
                (__attribute__((address_space(3))) void*)&Ks[buf][wid * 128 + it * 64],     \
                16, 0, 0);                                                                  \
            __builtin_amdgcn_global_load_lds(                                               \
                (const __attribute__((address_space(1))) void*)(vbase + (size_t)row * S_DIM + (j0) + c * 8), \
                (__attribute__((address_space(3))) void*)&Vs[buf][wid * 128 + it * 64],     \
                16, 0, 0);                                                                  \
        }                                                                                   \
    }

    STAGE(0, 0)
    __syncthreads();   // drains vmcnt(0): tile 0 resident
    int cur = 0;

    for (int jt = 0; jt < 8; ++jt) {
        if (jt < 7) STAGE(cur ^ 1, (jt + 1) * 64)   // async prefetch overlaps compute

        // S = Q K^T : mfma(Q-frag, K-frag) -> D[i][j], i=(lane>>4)*4+r, j=lane&15 (+16ct)
        f32x4 sacc[4];
#pragma unroll
        for (int ct = 0; ct < 4; ++ct) sacc[ct] = (f32x4){0.f, 0.f, 0.f, 0.f};
#pragma unroll
        for (int kk = 0; kk < 2; ++kk) {
#pragma unroll
            for (int ct = 0; ct < 4; ++ct) {
                int row = ct * 16 + (lane & 15);
                int c = kk * 4 + (lane >> 4);
                short8 kf = *reinterpret_cast<const short8*>(&Ks[cur][row * 8 + (c ^ (lane & 7))]);
                sacc[ct] = __builtin_amdgcn_mfma_f32_16x16x32_bf16(qf[kk], kf, sacc[ct], 0, 0, 0);
            }
        }
        // P = exp(S/temp); accumulate per-lane partial row sums; stash bf16 P in
        // swizzled per-wave LDS for the transpose to A-fragment layout.
#pragma unroll
        for (int ct = 0; ct < 4; ++ct) {
#pragma unroll
            for (int r = 0; r < 4; ++r) {
                float p = __expf(sacc[ct][r] * 0.125f);
                ps[r] += p;
                int i = (lane >> 4) * 4 + r;
                int j = (lane & 15) + 16 * ct;
                psw[i * 64 + (j ^ ((i & 7) << 3))] = f2bf(p);
            }
        }
        // O += P V : mfma(P-frag, Vt-frag)
#pragma unroll
        for (int jh = 0; jh < 2; ++jh) {
            int c = jh * 4 + (lane >> 4);
            short8 pf = *reinterpret_cast<const short8*>(&Ps[wid * 128 + (lane & 15) * 8 + (c ^ (lane & 7))]);
#pragma unroll
            for (int dt = 0; dt < 4; ++dt) {
                int row = dt * 16 + (lane & 15);
                short8 vf = *reinterpret_cast<const short8*>(&Vs[cur][row * 8 + (c ^ (lane & 7))]);
                oacc[dt] = __builtin_amdgcn_mfma_f32_16x16x32_bf16(pf, vf, oacc[dt], 0, 0, 0);
            }
        }

        if (jt < 7) {
            __syncthreads();   // staged tile resident AND all waves done reading buf cur
            cur ^= 1;
        }
    }
#undef STAGE

    // Full row sums (16-lane butterfly, once per kernel) and normalize.
#pragma unroll
    for (int r = 0; r < 4; ++r) {
#pragma unroll
        for (int off = 1; off < 16; off <<= 1) ps[r] += __shfl_xor(ps[r], off);
        ps[r] = 1.0f / ps[r];
    }
#pragma unroll
    for (int dt = 0; dt < 4; ++dt) {
#pragma unroll
        for (int r = 0; r < 4; ++r) {
            int srow = i0 + (lane >> 4) * 4 + r;
            size_t oidx = (size_t)srow * (T_DIM * D_DIM) + (size_t)t * D_DIM + h * HD + dt * 16 + (lane & 15);
            xt[oidx] = x[oidx] + oacc[dt][r] * ps[r];
        }
    }
}

// ---------------------------------------------------------------------------
extern "C" void kernel_launch(void* const* d_in, const int* in_sizes, int n_in,
                              void* d_out, int out_size, void* d_ws, size_t ws_size,
                              hipStream_t stream) {
    const float* x  = (const float*)d_in[0];
    const float* wq = (const float*)d_in[1];
    const float* wk = (const float*)d_in[2];
    const float* wv = (const float*)d_in[3];
    const float* g1 = (const float*)d_in[4];
    const float* be1 = (const float*)d_in[5];
    const float* g2 = (const float*)d_in[6];
    const float* be2 = (const float*)d_in[7];
    const float* w1 = (const float*)d_in[8];
    const float* b1 = (const float*)d_in[9];
    const float* w2 = (const float*)d_in[10];
    const float* b2 = (const float*)d_in[11];
    float* out = (float*)d_out;

    char* ws = (char*)d_ws;
    const size_t MB = 1024ull * 1024;
    ushort* xnb = (ushort*)ws;                // 32 MB: LN1 out, later LN2 out
    ushort* qb  = (ushort*)(ws + 32 * MB);    // 32 MB: Q [T,S,D]; later FFN hidden
    ushort* kb  = (ushort*)(ws + 64 * MB);    // 32 MB: K [T,S,D]
    ushort* vtb = (ushort*)(ws + 96 * MB);    // 32 MB: V^T [T,D,S]
    ushort* wb  = (ushort*)(ws + 128 * MB);   // 5 x 64K bf16 weights
    ushort* wqb = wb;
    ushort* wkb = wb + 65536;
    ushort* wvb = wb + 2 * 65536;
    ushort* w1b = wb + 3 * 65536;
    ushort* w2b = wb + 4 * 65536;
    ushort* hb  = qb;

    dim3 gg(NROWS / 128, D_DIM / 128);

    wconv<<<dim3(64, 5), 256, 0, stream>>>(wq, wk, wv, w1, w2, wb);
    ln_bf16<<<NROWS / 4, 256, 0, stream>>>(x, g1, be1, xnb);
    gemm_bf16<OUT_QK><<<gg, 256, 0, stream>>>(xnb, wqb, nullptr, nullptr, qb);
    gemm_bf16<OUT_QK><<<gg, 256, 0, stream>>>(xnb, wkb, nullptr, nullptr, kb);
    gemm_bf16<OUT_VT><<<gg, 256, 0, stream>>>(xnb, wvb, nullptr, nullptr, vtb);
    attn_mfma<<<dim3(S_DIM / 64, 4, T_DIM), 256, 0, stream>>>(qb, kb, vtb, x, out);
    ln_bf16<<<NROWS / 4, 256, 0, stream>>>(out, g2, be2, xnb);
    gemm_bf16<OUT_H><<<gg, 256, 0, stream>>>(xnb, w1b, b1, nullptr, hb);
    gemm_bf16<OUT_FFN2><<<gg, 256, 0, stream>>>(hb, w2b, b2, out, out);
}

// Round 10
// 385.271 us; speedup vs baseline: 1.3713x; 1.0502x over previous
//
#include <hip/hip_runtime.h>
#include <hip/hip_bf16.h>

typedef __attribute__((ext_vector_type(8))) short short8;   // 8 bf16 = 4 VGPR (guide §3)
typedef __attribute__((ext_vector_type(4))) float f32x4;

#define S_DIM 512
#define T_DIM 128
#define D_DIM 256
#define HD 64
#define NROWS 65536
static constexpr float LN_EPS = 1e-5f;

static __device__ __forceinline__ ushort f2bf(float f) {
    uint32_t b = __float_as_uint(f);
    b += 0x7FFF + ((b >> 16) & 1);   // RNE
    return (ushort)(b >> 16);
}

// packed f32x2 -> bf16x2 (RNE), T12 recipe: no builtin on gfx950, inline asm
static __device__ __forceinline__ uint cvtpk(float lo, float hi) {
    uint r;
    asm("v_cvt_pk_bf16_f32 %0, %1, %2" : "=v"(r) : "v"(lo), "v"(hi));
    return r;
}

// ---------------------------------------------------------------------------
// LayerNorm fp32 -> bf16. One wave per 256-row; 4 rows per block.
// ---------------------------------------------------------------------------
__global__ __launch_bounds__(256) void ln_bf16(const float* __restrict__ x,
                                               const float* __restrict__ g,
                                               const float* __restrict__ b,
                                               ushort* __restrict__ out) {
    int row = blockIdx.x * 4 + (threadIdx.x >> 6);
    int lane = threadIdx.x & 63;
    size_t base = (size_t)row * D_DIM + lane * 4;
    float4 xv = *reinterpret_cast<const float4*>(x + base);
    float s = xv.x + xv.y + xv.z + xv.w;
    float q = xv.x * xv.x + xv.y * xv.y + xv.z * xv.z + xv.w * xv.w;
#pragma unroll
    for (int off = 32; off > 0; off >>= 1) {
        s += __shfl_xor(s, off);
        q += __shfl_xor(q, off);
    }
    float mu = s * (1.0f / D_DIM);
    float var = q * (1.0f / D_DIM) - mu * mu;
    float rstd = rsqrtf(var + LN_EPS);
    float4 gv = *reinterpret_cast<const float4*>(g + lane * 4);
    float4 bv = *reinterpret_cast<const float4*>(b + lane * 4);
    ushort4 o = make_ushort4(f2bf((xv.x - mu) * rstd * gv.x + bv.x),
                             f2bf((xv.y - mu) * rstd * gv.y + bv.y),
                             f2bf((xv.z - mu) * rstd * gv.z + bv.z),
                             f2bf((xv.w - mu) * rstd * gv.w + bv.w));
    *reinterpret_cast<ushort4*>(out + base) = o;
}

// ---------------------------------------------------------------------------
// Weight conversion fp32 -> bf16 (5 x 256x256)
// ---------------------------------------------------------------------------
__global__ __launch_bounds__(256) void wconv(const float* __restrict__ w0, const float* __restrict__ w1,
                                             const float* __restrict__ w2, const float* __restrict__ w3,
                                             const float* __restrict__ w4, ushort* __restrict__ dst) {
    const float* s;
    switch (blockIdx.y) {
        case 0: s = w0; break;
        case 1: s = w1; break;
        case 2: s = w2; break;
        case 3: s = w3; break;
        default: s = w4; break;
    }
    int idx = (blockIdx.x * 256 + threadIdx.x) * 4;
    float4 v = *reinterpret_cast<const float4*>(s + idx);
    ushort4 o = make_ushort4(f2bf(v.x), f2bf(v.y), f2bf(v.z), f2bf(v.w));
    *reinterpret_cast<ushort4*>(dst + (size_t)blockIdx.y * 65536 + idx) = o;
}

// ---------------------------------------------------------------------------
// bf16 MFMA GEMM: C[m][n] = sum_k A[m][k] * W[n][k]  (W row-major [N][K])
// BM=BN=128, BK=64, 256 thr (4 waves, each 64x64 out).
// LDS tiles XOR-swizzled (chunk ^= row&7) on both write and read sides.
// OUT_QK / OUT_VT use t-major row blocking (block = fixed t, 128 consecutive
// s). OUT_VT additionally stores s at PV-permuted position within each
// 64-block: p = pi^-1(s), bit shuffle of bits 4:2 (bits 1:0 preserved so the
// ushort4 stores stay contiguous). Attention reads V^T linearly; the
// permutation makes its PV A-fragment fully lane-local.
// ---------------------------------------------------------------------------
enum { OUT_QK = 0, OUT_VT = 1, OUT_H = 2, OUT_FFN2 = 3 };

template <int MODE>
__global__ __launch_bounds__(256) void gemm_bf16(const ushort* __restrict__ A,
                                                 const ushort* __restrict__ W,
                                                 const float* __restrict__ bias,
                                                 const float* __restrict__ res,
                                                 void* __restrict__ outp) {
    __shared__ uint4 As[1024];   // 128 rows x 8 chunks of 16B
    __shared__ uint4 Bs[1024];
    const int tid = threadIdx.x;
    const int lane = tid & 63;
    const int wid = tid >> 6;
    const int m0 = blockIdx.x * 128;
    const int n0 = blockIdx.y * 128;
    const int wm = (wid >> 1) * 64;
    const int wn = (wid & 1) * 64;

    constexpr bool TMAJ = (MODE == OUT_VT || MODE == OUT_QK);
    // t-major modes: virtual row order r' = t*S + s (t fixed per block)
    const int tblk = m0 >> 9;        // m0 / S_DIM
    const int s0 = m0 & (S_DIM - 1);

    f32x4 acc[4][4];
#pragma unroll
    for (int mi = 0; mi < 4; ++mi)
#pragma unroll
        for (int ni = 0; ni < 4; ++ni) acc[mi][ni] = (f32x4){0.f, 0.f, 0.f, 0.f};

    const ushort* Abase = TMAJ ? A + ((size_t)s0 * T_DIM + tblk) * D_DIM
                               : A + (size_t)m0 * D_DIM;
    const size_t Astride = TMAJ ? (size_t)T_DIM * D_DIM : (size_t)D_DIM;
    const ushort* Wbase = W + (size_t)n0 * D_DIM;
    uint4 ra[4], rb[4];

#define GLOAD(dstreg, base, stride, k0)                                                     \
    {                                                                                       \
        _Pragma("unroll") for (int it = 0; it < 4; ++it) {                                  \
            int L = it * 256 + tid;                                                         \
            int row = L >> 3, c = L & 7;                                                    \
            dstreg[it] = *reinterpret_cast<const uint4*>(base + (size_t)row * (stride) + (k0) + c * 8); \
        }                                                                                   \
    }
#define SWRITE(lds, srcreg)                                                                 \
    {                                                                                       \
        _Pragma("unroll") for (int it = 0; it < 4; ++it) {                                  \
            int L = it * 256 + tid;                                                         \
            int row = L >> 3, c = L & 7;                                                    \
            lds[row * 8 + (c ^ (row & 7))] = srcreg[it];                                    \
        }                                                                                   \
    }

    GLOAD(ra, Abase, Astride, 0)
    GLOAD(rb, Wbase, D_DIM, 0)
    for (int ks = 0; ks < 4; ++ks) {
        __syncthreads();
        SWRITE(As, ra)
        SWRITE(Bs, rb)
        __syncthreads();
        if (ks < 3) {
            GLOAD(ra, Abase, Astride, (ks + 1) * 64)
            GLOAD(rb, Wbase, D_DIM, (ks + 1) * 64)
        }
#pragma unroll
        for (int kk = 0; kk < 2; ++kk) {
            short8 af[4], bf[4];
#pragma unroll
            for (int mi = 0; mi < 4; ++mi) {
                int row = wm + mi * 16 + (lane & 15);
                int c = kk * 4 + (lane >> 4);
                af[mi] = *reinterpret_cast<const short8*>(&As[row * 8 + (c ^ (lane & 7))]);
            }
#pragma unroll
            for (int ni = 0; ni < 4; ++ni) {
                int row = wn + ni * 16 + (lane & 15);
                int c = kk * 4 + (lane >> 4);
                bf[ni] = *reinterpret_cast<const short8*>(&Bs[row * 8 + (c ^ (lane & 7))]);
            }
#pragma unroll
            for (int mi = 0; mi < 4; ++mi)
#pragma unroll
                for (int ni = 0; ni < 4; ++ni)
                    acc[mi][ni] = __builtin_amdgcn_mfma_f32_16x16x32_bf16(af[mi], bf[ni], acc[mi][ni], 0, 0, 0);
        }
    }

    // Epilogue. D layout: row=(lane>>4)*4+r, col=lane&15 (m89).
#pragma unroll
    for (int mi = 0; mi < 4; ++mi) {
#pragma unroll
        for (int ni = 0; ni < 4; ++ni) {
            int gn = n0 + wn + ni * 16 + (lane & 15);
            if (MODE == OUT_VT) {
                // 4 accum rows = 4 consecutive s at fixed (t, gn); store at
                // pi^-1(s): bits[4:3]=s[3:2], bit[2]=s[4]; bits 1:0 kept.
                int s = s0 + wm + mi * 16 + (lane >> 4) * 4;
                int p = (s & ~28) | ((s & 12) << 1) | ((s & 16) >> 2);
                ushort4 o = make_ushort4(f2bf(acc[mi][ni][0]), f2bf(acc[mi][ni][1]),
                                         f2bf(acc[mi][ni][2]), f2bf(acc[mi][ni][3]));
                *reinterpret_cast<ushort4*>(
                    &((ushort*)outp)[((size_t)tblk * D_DIM + gn) * S_DIM + p]) = o;
            } else if (MODE == OUT_QK) {
#pragma unroll
                for (int r = 0; r < 4; ++r) {
                    int s = s0 + wm + mi * 16 + (lane >> 4) * 4 + r;
                    ((ushort*)outp)[(size_t)tblk * (S_DIM * D_DIM) + (size_t)s * D_DIM + gn] =
                        f2bf(acc[mi][ni][r]);
                }
            } else {
#pragma unroll
                for (int r = 0; r < 4; ++r) {
                    int gm = m0 + wm + mi * 16 + (lane >> 4) * 4 + r;
                    float v = acc[mi][ni][r];
                    if (MODE == OUT_H) {
                        v += bias[gn];
                        v = fmaxf(v, 0.f);
                        ((ushort*)outp)[(size_t)gm * D_DIM + gn] = f2bf(v);
                    } else {
                        v += bias[gn] + res[(size_t)gm * D_DIM + gn];
                        ((float*)outp)[(size_t)gm * D_DIM + gn] = v;
                    }
                }
            }
        }
    }
#undef GLOAD
#undef SWRITE
}

// ---------------------------------------------------------------------------
// MFMA flash attention, fully in-register softmax.
// Grid (x=t, y=i-chunk, z=h): linear id = t + 128 i + 1024 h, so all 32 blocks
// of one t land on XCD (t%8): K/V i-sharers AND h-write-partners co-located.
// Swapped QK^T (mfma(K,Q) -> S^T): lane holds S[i=lane&15][ct*16+g*4+r].
// PV uses a within-tile j-permutation pi (baked into V^T storage by OUT_VT):
// pi(jh*32+g*8+2w+b) = (2jh+(w>>1))*16+4g+2(w&1)+b, which makes the PV
// A-fragment exactly {pk[2jh][0],pk[2jh][1],pk[2jh+1][0],pk[2jh+1][1]} —
// lane-local, no LDS/permute. K/V double-buffered via global_load_lds
// (linear dest + inverse-swizzled global source, rule #21).
// ---------------------------------------------------------------------------
__global__ __launch_bounds__(256) void attn_mfma(const ushort* __restrict__ qb,
                                                 const ushort* __restrict__ kb,
                                                 const ushort* __restrict__ vtb,
                                                 const float* __restrict__ x,
                                                 float* __restrict__ xt) {
    __shared__ uint4 Ks[2][512];   // 64 rows x 8 chunks, double-buffered
    __shared__ uint4 Vs[2][512];
    const int tid = threadIdx.x;
    const int lane = tid & 63;
    const int wid = tid >> 6;
    const int t = blockIdx.x;
    const int h = blockIdx.z;
    const int i0 = blockIdx.y * 64 + wid * 16;
    constexpr float SC = 0.125f * 1.44269504089f;   // fold temp into exp2

    short8 qf[2];
    {
        const ushort* qrow = qb + ((size_t)t * S_DIM + i0 + (lane & 15)) * D_DIM + h * HD;
#pragma unroll
        for (int kk = 0; kk < 2; ++kk)
            qf[kk] = *reinterpret_cast<const short8*>(qrow + kk * 32 + (lane >> 4) * 8);
    }

    f32x4 oacc[4];
#pragma unroll
    for (int dt = 0; dt < 4; ++dt) oacc[dt] = (f32x4){0.f, 0.f, 0.f, 0.f};
    float psl = 0.f;   // partial row-sum for row i = i0 + (lane&15)

    const ushort* kbase = kb + (size_t)t * (S_DIM * D_DIM) + h * HD;
    const ushort* vbase = vtb + ((size_t)t * D_DIM + h * HD) * S_DIM;

#define STAGE(buf, j0)                                                                      \
    {                                                                                       \
        _Pragma("unroll") for (int it = 0; it < 2; ++it) {                                  \
            int slot = wid * 128 + it * 64 + lane;                                          \
            int row = slot >> 3;                                                            \
            int c = (slot & 7) ^ (row & 7);                                                 \
            __builtin_amdgcn_global_load_lds(                                               \
                (const __attribute__((address_space(1))) void*)(kbase + (size_t)((j0) + row) * D_DIM + c * 8), \
                (__attribute__((address_space(3))) void*)&Ks[buf][wid * 128 + it * 64],     \
                16, 0, 0);                                                                  \
            __builtin_amdgcn_global_load_lds(                                               \
                (const __attribute__((address_space(1))) void*)(vbase + (size_t)row * S_DIM + (j0) + c * 8), \
                (__attribute__((address_space(3))) void*)&Vs[buf][wid * 128 + it * 64],     \
                16, 0, 0);                                                                  \
        }                                                                                   \
    }

    STAGE(0, 0)
    __syncthreads();   // drains vmcnt(0): tile 0 resident
    int cur = 0;

    for (int jt = 0; jt < 8; ++jt) {
        if (jt < 7) STAGE(cur ^ 1, (jt + 1) * 64)   // async prefetch overlaps compute

        // S^T = mfma(K, Q): lane holds S[i=lane&15][j0 + ct*16 + (lane>>4)*4 + r]
        f32x4 sacc[4];
#pragma unroll
        for (int ct = 0; ct < 4; ++ct) sacc[ct] = (f32x4){0.f, 0.f, 0.f, 0.f};
#pragma unroll
        for (int kk = 0; kk < 2; ++kk) {
#pragma unroll
            for (int ct = 0; ct < 4; ++ct) {
                int row = ct * 16 + (lane & 15);
                int c = kk * 4 + (lane >> 4);
                short8 kf = *reinterpret_cast<const short8*>(&Ks[cur][row * 8 + (c ^ (lane & 7))]);
                sacc[ct] = __builtin_amdgcn_mfma_f32_16x16x32_bf16(kf, qf[kk], sacc[ct], 0, 0, 0);
            }
        }

        // P = exp2(S*SC); pack register pairs to bf16x2 (all lane-local)
        uint pk[4][2];
#pragma unroll
        for (int ct = 0; ct < 4; ++ct) {
            float p0 = exp2f(sacc[ct][0] * SC);
            float p1 = exp2f(sacc[ct][1] * SC);
            float p2 = exp2f(sacc[ct][2] * SC);
            float p3 = exp2f(sacc[ct][3] * SC);
            psl += (p0 + p1) + (p2 + p3);
            pk[ct][0] = cvtpk(p0, p1);
            pk[ct][1] = cvtpk(p2, p3);
        }

        // O += P V : A-frag is lane-local under pi; V storage pre-permuted
#pragma unroll
        for (int jh = 0; jh < 2; ++jh) {
            int4 pd;
            pd.x = (int)pk[2 * jh][0];
            pd.y = (int)pk[2 * jh][1];
            pd.z = (int)pk[2 * jh + 1][0];
            pd.w = (int)pk[2 * jh + 1][1];
            short8 pf = *reinterpret_cast<short8*>(&pd);
            int c = jh * 4 + (lane >> 4);
#pragma unroll
            for (int dt = 0; dt < 4; ++dt) {
                int row = dt * 16 + (lane & 15);
                short8 vf = *reinterpret_cast<const short8*>(&Vs[cur][row * 8 + (c ^ (lane & 7))]);
                oacc[dt] = __builtin_amdgcn_mfma_f32_16x16x32_bf16(pf, vf, oacc[dt], 0, 0, 0);
            }
        }

        if (jt < 7) {
            __syncthreads();   // staged tile resident AND all waves done with buf cur
            cur ^= 1;
        }
    }
#undef STAGE

    // Row sums: lanes {l, l^16, l^32, l^48} share row i=lane&15
    psl += __shfl_xor(psl, 16);
    psl += __shfl_xor(psl, 32);
    float inv = 1.0f / psl;
    float invr[4];
#pragma unroll
    for (int r = 0; r < 4; ++r)
        invr[r] = __int_as_float(__builtin_amdgcn_ds_bpermute(
            (((lane >> 4) * 4 + r) << 2), __float_as_int(inv)));

#pragma unroll
    for (int dt = 0; dt < 4; ++dt) {
#pragma unroll
        for (int r = 0; r < 4; ++r) {
            int srow = i0 + (lane >> 4) * 4 + r;
            size_t oidx = (size_t)srow * (T_DIM * D_DIM) + (size_t)t * D_DIM + h * HD + dt * 16 + (lane & 15);
            xt[oidx] = x[oidx] + oacc[dt][r] * invr[r];
        }
    }
}

// ---------------------------------------------------------------------------
extern "C" void kernel_launch(void* const* d_in, const int* in_sizes, int n_in,
                              void* d_out, int out_size, void* d_ws, size_t ws_size,
                              hipStream_t stream) {
    const float* x  = (const float*)d_in[0];
    const float* wq = (const float*)d_in[1];
    const float* wk = (const float*)d_in[2];
    const float* wv = (const float*)d_in[3];
    const float* g1 = (const float*)d_in[4];
    const float* be1 = (const float*)d_in[5];
    const float* g2 = (const float*)d_in[6];
    const float* be2 = (const float*)d_in[7];
    const float* w1 = (const float*)d_in[8];
    const float* b1 = (const float*)d_in[9];
    const float* w2 = (const float*)d_in[10];
    const float* b2 = (const float*)d_in[11];
    float* out = (float*)d_out;

    char* ws = (char*)d_ws;
    const size_t MB = 1024ull * 1024;
    ushort* xnb = (ushort*)ws;                // 32 MB: LN1 out, later LN2 out
    ushort* qb  = (ushort*)(ws + 32 * MB);    // 32 MB: Q [T,S,D]; later FFN hidden
    ushort* kb  = (ushort*)(ws + 64 * MB);    // 32 MB: K [T,S,D]
    ushort* vtb = (ushort*)(ws + 96 * MB);    // 32 MB: V^T [T,D,S] (pi-permuted s)
    ushort* wb  = (ushort*)(ws + 128 * MB);   // 5 x 64K bf16 weights
    ushort* wqb = wb;
    ushort* wkb = wb + 65536;
    ushort* wvb = wb + 2 * 65536;
    ushort* w1b = wb + 3 * 65536;
    ushort* w2b = wb + 4 * 65536;
    ushort* hb  = qb;

    dim3 gg(NROWS / 128, D_DIM / 128);

    wconv<<<dim3(64, 5), 256, 0, stream>>>(wq, wk, wv, w1, w2, wb);
    ln_bf16<<<NROWS / 4, 256, 0, stream>>>(x, g1, be1, xnb);
    gemm_bf16<OUT_QK><<<gg, 256, 0, stream>>>(xnb, wqb, nullptr, nullptr, qb);
    gemm_bf16<OUT_QK><<<gg, 256, 0, stream>>>(xnb, wkb, nullptr, nullptr, kb);
    gemm_bf16<OUT_VT><<<gg, 256, 0, stream>>>(xnb, wvb, nullptr, nullptr, vtb);
    attn_mfma<<<dim3(T_DIM, S_DIM / 64, 4), 256, 0, stream>>>(qb, kb, vtb, x, out);
    ln_bf16<<<NROWS / 4, 256, 0, stream>>>(out, g2, be2, xnb);
    gemm_bf16<OUT_H><<<gg, 256, 0, stream>>>(xnb, w1b, b1, nullptr, hb);
    gemm_bf16<OUT_FFN2><<<gg, 256, 0, stream>>>(hb, w2b, b2, out, out);
}

// Round 11
// 252.143 us; speedup vs baseline: 2.0954x; 1.5280x over previous
//
#include <hip/hip_runtime.h>
#include <hip/hip_bf16.h>

typedef __attribute__((ext_vector_type(8))) short short8;   // 8 bf16 = 4 VGPR
typedef __attribute__((ext_vector_type(4))) float f32x4;

#define S_DIM 512
#define T_DIM 128
#define D_DIM 256
#define HD 64
#define NROWS 65536
static constexpr float LN_EPS = 1e-5f;
static constexpr float SCQ = 0.125f * 1.44269504089f;   // temp^-1 * log2(e), folded into Q

#define AS1 __attribute__((address_space(1)))
#define AS3 __attribute__((address_space(3)))

static __device__ __forceinline__ ushort f2bf(float f) {
    uint32_t b = __float_as_uint(f);
    b += 0x7FFF + ((b >> 16) & 1);   // RNE
    return (ushort)(b >> 16);
}

static __device__ __forceinline__ uint cvtpk(float lo, float hi) {
    uint r;
    asm("v_cvt_pk_bf16_f32 %0, %1, %2" : "=v"(r) : "v"(lo), "v"(hi));
    return r;
}

// ---------------------------------------------------------------------------
// LayerNorm fp32 -> bf16. One wave per 256-row; 4 rows per block.
// ---------------------------------------------------------------------------
__global__ __launch_bounds__(256) void ln_bf16(const float* __restrict__ x,
                                               const float* __restrict__ g,
                                               const float* __restrict__ b,
                                               ushort* __restrict__ out) {
    int row = blockIdx.x * 4 + (threadIdx.x >> 6);
    int lane = threadIdx.x & 63;
    size_t base = (size_t)row * D_DIM + lane * 4;
    float4 xv = *reinterpret_cast<const float4*>(x + base);
    float s = xv.x + xv.y + xv.z + xv.w;
    float q = xv.x * xv.x + xv.y * xv.y + xv.z * xv.z + xv.w * xv.w;
#pragma unroll
    for (int off = 32; off > 0; off >>= 1) {
        s += __shfl_xor(s, off);
        q += __shfl_xor(q, off);
    }
    float mu = s * (1.0f / D_DIM);
    float var = q * (1.0f / D_DIM) - mu * mu;
    float rstd = rsqrtf(var + LN_EPS);
    float4 gv = *reinterpret_cast<const float4*>(g + lane * 4);
    float4 bv = *reinterpret_cast<const float4*>(b + lane * 4);
    ushort4 o = make_ushort4(f2bf((xv.x - mu) * rstd * gv.x + bv.x),
                             f2bf((xv.y - mu) * rstd * gv.y + bv.y),
                             f2bf((xv.z - mu) * rstd * gv.z + bv.z),
                             f2bf((xv.w - mu) * rstd * gv.w + bv.w));
    *reinterpret_cast<ushort4*>(out + base) = o;
}

// ---------------------------------------------------------------------------
// Weight conversion fp32 -> bf16 (5 x 256x256)
// ---------------------------------------------------------------------------
__global__ __launch_bounds__(256) void wconv(const float* __restrict__ w0, const float* __restrict__ w1,
                                             const float* __restrict__ w2, const float* __restrict__ w3,
                                             const float* __restrict__ w4, ushort* __restrict__ dst) {
    const float* s;
    switch (blockIdx.y) {
        case 0: s = w0; break;
        case 1: s = w1; break;
        case 2: s = w2; break;
        case 3: s = w3; break;
        default: s = w4; break;
    }
    int idx = (blockIdx.x * 256 + threadIdx.x) * 4;
    float4 v = *reinterpret_cast<const float4*>(s + idx);
    ushort4 o = make_ushort4(f2bf(v.x), f2bf(v.y), f2bf(v.z), f2bf(v.w));
    *reinterpret_cast<ushort4*>(dst + (size_t)blockIdx.y * 65536 + idx) = o;
}

// ---------------------------------------------------------------------------
// bf16 MFMA GEMM, m97-style global_load_lds staging (linear LDS dest +
// inverse-swizzled global source, rule #21), single-buffered, 2 barriers/step.
// BM=BN=128, BK=64, 256 thr (4 waves, 64x64 out each).
// M_QKV: fused Q/K/V projection. Grid (512, 6): y>>1 selects W (wq/wk/wv,
//   contiguous) and output (qb/kb/vtb, contiguous 16M ushorts apart).
//   A is t-major (r' = t*S + s). Q epilogue pre-scales by SCQ (attn exp2 fold).
//   V epilogue stores pi-permuted s (lane-local PV A-frag in attention).
// M_H / M_FFN2: FFN layers, A row-major, grid (512, 2).
// ---------------------------------------------------------------------------
enum { M_QKV = 0, M_H = 1, M_FFN2 = 2 };

template <int MODE>
__global__ __launch_bounds__(256) void gemm_m97(const ushort* __restrict__ A,
                                                const ushort* __restrict__ Wall,
                                                const float* __restrict__ bias,
                                                const float* __restrict__ res,
                                                void* __restrict__ outp) {
    __shared__ uint4 As[1024];   // 128 rows x 8 chunks of 16B
    __shared__ uint4 Bs[1024];
    const int tid = threadIdx.x;
    const int lane = tid & 63;
    const int wid = tid >> 6;
    const int y = blockIdx.y;
    const int wm = (wid >> 1) * 64;
    const int wn = (wid & 1) * 64;

    constexpr bool QKV = (MODE == M_QKV);
    const int tblk = blockIdx.x >> 2;          // QKV: fixed t per block
    const int s0 = (blockIdx.x & 3) * 128;     // QKV: s-panel
    const int m0 = blockIdx.x * 128;

    const ushort* Abase = QKV ? A + ((size_t)s0 * T_DIM + tblk) * D_DIM
                              : A + (size_t)m0 * D_DIM;
    const size_t Ast = QKV ? (size_t)T_DIM * D_DIM : (size_t)D_DIM;
    const int n0 = QKV ? (y & 1) * 128 : y * 128;
    const ushort* Wbase = (QKV ? Wall + (size_t)(y >> 1) * 65536 : Wall) + (size_t)n0 * D_DIM;

    f32x4 acc[4][4];
#pragma unroll
    for (int mi = 0; mi < 4; ++mi)
#pragma unroll
        for (int ni = 0; ni < 4; ++ni) acc[mi][ni] = (f32x4){0.f, 0.f, 0.f, 0.f};

    const int srow = tid >> 3;   // 0..31 per iter-block
    const int sc = tid & 7;

    for (int ks = 0; ks < 4; ++ks) {
        const int k0 = ks * 64;
#pragma unroll
        for (int it = 0; it < 4; ++it) {
            int row = it * 32 + srow;
            int c = sc ^ (row & 7);
            __builtin_amdgcn_global_load_lds(
                (const AS1 void*)(Abase + (size_t)row * Ast + k0 + c * 8),
                (AS3 void*)&As[it * 256 + wid * 64], 16, 0, 0);
            __builtin_amdgcn_global_load_lds(
                (const AS1 void*)(Wbase + (size_t)row * D_DIM + k0 + c * 8),
                (AS3 void*)&Bs[it * 256 + wid * 64], 16, 0, 0);
        }
        __syncthreads();   // drain vmcnt: tile resident
#pragma unroll
        for (int kk = 0; kk < 2; ++kk) {
            short8 af[4], bf[4];
#pragma unroll
            for (int mi = 0; mi < 4; ++mi) {
                int row = wm + mi * 16 + (lane & 15);
                int c = kk * 4 + (lane >> 4);
                af[mi] = *reinterpret_cast<const short8*>(&As[row * 8 + (c ^ (row & 7))]);
            }
#pragma unroll
            for (int ni = 0; ni < 4; ++ni) {
                int row = wn + ni * 16 + (lane & 15);
                int c = kk * 4 + (lane >> 4);
                bf[ni] = *reinterpret_cast<const short8*>(&Bs[row * 8 + (c ^ (row & 7))]);
            }
#pragma unroll
            for (int mi = 0; mi < 4; ++mi)
#pragma unroll
                for (int ni = 0; ni < 4; ++ni)
                    acc[mi][ni] = __builtin_amdgcn_mfma_f32_16x16x32_bf16(af[mi], bf[ni], acc[mi][ni], 0, 0, 0);
        }
        __syncthreads();   // all reads done before next stage overwrites
    }

    // Epilogue. D layout: row=(lane>>4)*4+r, col=lane&15 (m89).
    if (MODE == M_QKV) {
        ushort* outb = (ushort*)outp + (size_t)(y >> 1) * 16777216;
        const bool isV = (y >= 4);
        const float scale = (y < 2) ? SCQ : 1.0f;
#pragma unroll
        for (int mi = 0; mi < 4; ++mi) {
#pragma unroll
            for (int ni = 0; ni < 4; ++ni) {
                int gn = n0 + wn + ni * 16 + (lane & 15);
                if (isV) {
                    // pi^-1(s): bits[4:3]=s[3:2], bit[2]=s[4]; bits 1:0 kept
                    int s = s0 + wm + mi * 16 + (lane >> 4) * 4;
                    int p = (s & ~28) | ((s & 12) << 1) | ((s & 16) >> 2);
                    ushort4 o = make_ushort4(f2bf(acc[mi][ni][0]), f2bf(acc[mi][ni][1]),
                                             f2bf(acc[mi][ni][2]), f2bf(acc[mi][ni][3]));
                    *reinterpret_cast<ushort4*>(
                        &outb[((size_t)tblk * D_DIM + gn) * S_DIM + p]) = o;
                } else {
#pragma unroll
                    for (int r = 0; r < 4; ++r) {
                        int s = s0 + wm + mi * 16 + (lane >> 4) * 4 + r;
                        outb[(size_t)tblk * (S_DIM * D_DIM) + (size_t)s * D_DIM + gn] =
                            f2bf(acc[mi][ni][r] * scale);
                    }
                }
            }
        }
    } else {
#pragma unroll
        for (int mi = 0; mi < 4; ++mi) {
#pragma unroll
            for (int ni = 0; ni < 4; ++ni) {
                int gn = n0 + wn + ni * 16 + (lane & 15);
#pragma unroll
                for (int r = 0; r < 4; ++r) {
                    int gm = m0 + wm + mi * 16 + (lane >> 4) * 4 + r;
                    float v = acc[mi][ni][r];
                    if (MODE == M_H) {
                        v += bias[gn];
                        v = fmaxf(v, 0.f);
                        ((ushort*)outp)[(size_t)gm * D_DIM + gn] = f2bf(v);
                    } else {
                        v += bias[gn] + res[(size_t)gm * D_DIM + gn];
                        ((float*)outp)[(size_t)gm * D_DIM + gn] = v;
                    }
                }
            }
        }
    }
}

// ---------------------------------------------------------------------------
// MFMA flash attention, fully in-register softmax (round-10 structure).
// Grid (x=t, y=i-chunk, z=h): all 32 blocks of one t share an XCD.
// Q is pre-scaled by SCQ in the projection -> exp2f(sacc) directly.
// PV A-frag lane-local via pi-permuted V^T storage. K/V double-buffered via
// global_load_lds. jt loop fully unrolled (address CSE).
// ---------------------------------------------------------------------------
__global__ __launch_bounds__(256) void attn_mfma(const ushort* __restrict__ qb,
                                                 const ushort* __restrict__ kb,
                                                 const ushort* __restrict__ vtb,
                                                 const float* __restrict__ x,
                                                 float* __restrict__ xt) {
    __shared__ uint4 Ks[2][512];
    __shared__ uint4 Vs[2][512];
    const int tid = threadIdx.x;
    const int lane = tid & 63;
    const int wid = tid >> 6;
    const int t = blockIdx.x;
    const int h = blockIdx.z;
    const int i0 = blockIdx.y * 64 + wid * 16;

    short8 qf[2];
    {
        const ushort* qrow = qb + ((size_t)t * S_DIM + i0 + (lane & 15)) * D_DIM + h * HD;
#pragma unroll
        for (int kk = 0; kk < 2; ++kk)
            qf[kk] = *reinterpret_cast<const short8*>(qrow + kk * 32 + (lane >> 4) * 8);
    }

    f32x4 oacc[4];
#pragma unroll
    for (int dt = 0; dt < 4; ++dt) oacc[dt] = (f32x4){0.f, 0.f, 0.f, 0.f};
    float psl = 0.f;

    const ushort* kbase = kb + (size_t)t * (S_DIM * D_DIM) + h * HD;
    const ushort* vbase = vtb + ((size_t)t * D_DIM + h * HD) * S_DIM;

#define STAGE(buf, j0)                                                                      \
    {                                                                                       \
        _Pragma("unroll") for (int it = 0; it < 2; ++it) {                                  \
            int slot = wid * 128 + it * 64 + lane;                                          \
            int row = slot >> 3;                                                            \
            int c = (slot & 7) ^ (row & 7);                                                 \
            __builtin_amdgcn_global_load_lds(                                               \
                (const AS1 void*)(kbase + (size_t)((j0) + row) * D_DIM + c * 8),            \
                (AS3 void*)&Ks[buf][wid * 128 + it * 64], 16, 0, 0);                        \
            __builtin_amdgcn_global_load_lds(                                               \
                (const AS1 void*)(vbase + (size_t)row * S_DIM + (j0) + c * 8),              \
                (AS3 void*)&Vs[buf][wid * 128 + it * 64], 16, 0, 0);                        \
        }                                                                                   \
    }

    STAGE(0, 0)
    __syncthreads();
    int cur = 0;

#pragma unroll
    for (int jt = 0; jt < 8; ++jt) {
        if (jt < 7) STAGE(cur ^ 1, (jt + 1) * 64)

        f32x4 sacc[4];
#pragma unroll
        for (int ct = 0; ct < 4; ++ct) sacc[ct] = (f32x4){0.f, 0.f, 0.f, 0.f};
#pragma unroll
        for (int kk = 0; kk < 2; ++kk) {
#pragma unroll
            for (int ct = 0; ct < 4; ++ct) {
                int row = ct * 16 + (lane & 15);
                int c = kk * 4 + (lane >> 4);
                short8 kf = *reinterpret_cast<const short8*>(&Ks[cur][row * 8 + (c ^ (row & 7))]);
                sacc[ct] = __builtin_amdgcn_mfma_f32_16x16x32_bf16(kf, qf[kk], sacc[ct], 0, 0, 0);
            }
        }

        // P = exp2(S) (Q pre-scaled); pack pairs bf16x2, all lane-local
        uint pk[4][2];
#pragma unroll
        for (int ct = 0; ct < 4; ++ct) {
            float p0 = exp2f(sacc[ct][0]);
            float p1 = exp2f(sacc[ct][1]);
            float p2 = exp2f(sacc[ct][2]);
            float p3 = exp2f(sacc[ct][3]);
            psl += (p0 + p1) + (p2 + p3);
            pk[ct][0] = cvtpk(p0, p1);
            pk[ct][1] = cvtpk(p2, p3);
        }

        // O += P V : A-frag lane-local under pi (V^T pre-permuted)
#pragma unroll
        for (int jh = 0; jh < 2; ++jh) {
            int4 pd;
            pd.x = (int)pk[2 * jh][0];
            pd.y = (int)pk[2 * jh][1];
            pd.z = (int)pk[2 * jh + 1][0];
            pd.w = (int)pk[2 * jh + 1][1];
            short8 pf = *reinterpret_cast<short8*>(&pd);
            int c = jh * 4 + (lane >> 4);
#pragma unroll
            for (int dt = 0; dt < 4; ++dt) {
                int row = dt * 16 + (lane & 15);
                short8 vf = *reinterpret_cast<const short8*>(&Vs[cur][row * 8 + (c ^ (row & 7))]);
                oacc[dt] = __builtin_amdgcn_mfma_f32_16x16x32_bf16(pf, vf, oacc[dt], 0, 0, 0);
            }
        }

        if (jt < 7) {
            __syncthreads();
            cur ^= 1;
        }
    }
#undef STAGE

    // Row sums: lanes {l, l^16, l^32, l^48} share row i=lane&15
    psl += __shfl_xor(psl, 16);
    psl += __shfl_xor(psl, 32);
    float inv = 1.0f / psl;
    float invr[4];
#pragma unroll
    for (int r = 0; r < 4; ++r)
        invr[r] = __int_as_float(__builtin_amdgcn_ds_bpermute(
            (((lane >> 4) * 4 + r) << 2), __float_as_int(inv)));

#pragma unroll
    for (int dt = 0; dt < 4; ++dt) {
#pragma unroll
        for (int r = 0; r < 4; ++r) {
            int srow = i0 + (lane >> 4) * 4 + r;
            size_t oidx = (size_t)srow * (T_DIM * D_DIM) + (size_t)t * D_DIM + h * HD + dt * 16 + (lane & 15);
            xt[oidx] = x[oidx] + oacc[dt][r] * invr[r];
        }
    }
}

// ---------------------------------------------------------------------------
extern "C" void kernel_launch(void* const* d_in, const int* in_sizes, int n_in,
                              void* d_out, int out_size, void* d_ws, size_t ws_size,
                              hipStream_t stream) {
    const float* x  = (const float*)d_in[0];
    const float* wq = (const float*)d_in[1];
    const float* wk = (const float*)d_in[2];
    const float* wv = (const float*)d_in[3];
    const float* g1 = (const float*)d_in[4];
    const float* be1 = (const float*)d_in[5];
    const float* g2 = (const float*)d_in[6];
    const float* be2 = (const float*)d_in[7];
    const float* w1 = (const float*)d_in[8];
    const float* b1 = (const float*)d_in[9];
    const float* w2 = (const float*)d_in[10];
    const float* b2 = (const float*)d_in[11];
    float* out = (float*)d_out;

    char* ws = (char*)d_ws;
    const size_t MB = 1024ull * 1024;
    ushort* xnb = (ushort*)ws;                // 32 MB: LN1 out, later LN2 out
    ushort* qb  = (ushort*)(ws + 32 * MB);    // 32 MB: Q [T,S,D] (pre-scaled); later FFN hidden
    ushort* kb  = (ushort*)(ws + 64 * MB);    // 32 MB: K [T,S,D]
    ushort* vtb = (ushort*)(ws + 96 * MB);    // 32 MB: V^T [T,D,S] (pi-permuted s)
    ushort* wb  = (ushort*)(ws + 128 * MB);   // 5 x 64K bf16 weights (wq,wk,wv,w1,w2)
    ushort* w1b = wb + 3 * 65536;
    ushort* w2b = wb + 4 * 65536;
    ushort* hb  = qb;

    wconv<<<dim3(64, 5), 256, 0, stream>>>(wq, wk, wv, w1, w2, wb);
    ln_bf16<<<NROWS / 4, 256, 0, stream>>>(x, g1, be1, xnb);
    gemm_m97<M_QKV><<<dim3(512, 6), 256, 0, stream>>>(xnb, wb, nullptr, nullptr, qb);
    attn_mfma<<<dim3(T_DIM, S_DIM / 64, 4), 256, 0, stream>>>(qb, kb, vtb, x, out);
    ln_bf16<<<NROWS / 4, 256, 0, stream>>>(out, g2, be2, xnb);
    gemm_m97<M_H><<<dim3(512, 2), 256, 0, stream>>>(xnb, w1b, b1, nullptr, hb);
    gemm_m97<M_FFN2><<<dim3(512, 2), 256, 0, stream>>>(hb, w2b, b2, out, out);
}

// Round 12
// 237.413 us; speedup vs baseline: 2.2254x; 1.0620x over previous
//
#include <hip/hip_runtime.h>
#include <hip/hip_bf16.h>

typedef __attribute__((ext_vector_type(8))) short short8;   // 8 bf16 = 4 VGPR
typedef __attribute__((ext_vector_type(4))) float f32x4;

#define S_DIM 512
#define T_DIM 128
#define D_DIM 256
#define HD 64
#define NROWS 65536
static constexpr float LN_EPS = 1e-5f;
static constexpr float SCQ = 0.125f * 1.44269504089f;   // temp^-1 * log2(e), folded into Q

#define AS1 __attribute__((address_space(1)))
#define AS3 __attribute__((address_space(3)))

static __device__ __forceinline__ ushort f2bf(float f) {
    uint32_t b = __float_as_uint(f);
    b += 0x7FFF + ((b >> 16) & 1);   // RNE
    return (ushort)(b >> 16);
}

static __device__ __forceinline__ uint cvtpk(float lo, float hi) {
    uint r;
    asm("v_cvt_pk_bf16_f32 %0, %1, %2" : "=v"(r) : "v"(lo), "v"(hi));
    return r;
}

// ---------------------------------------------------------------------------
// LayerNorm fp32 -> bf16. One wave per 256-row; 4 rows per block.
// ---------------------------------------------------------------------------
__global__ __launch_bounds__(256) void ln_bf16(const float* __restrict__ x,
                                               const float* __restrict__ g,
                                               const float* __restrict__ b,
                                               ushort* __restrict__ out) {
    int row = blockIdx.x * 4 + (threadIdx.x >> 6);
    int lane = threadIdx.x & 63;
    size_t base = (size_t)row * D_DIM + lane * 4;
    float4 xv = *reinterpret_cast<const float4*>(x + base);
    float s = xv.x + xv.y + xv.z + xv.w;
    float q = xv.x * xv.x + xv.y * xv.y + xv.z * xv.z + xv.w * xv.w;
#pragma unroll
    for (int off = 32; off > 0; off >>= 1) {
        s += __shfl_xor(s, off);
        q += __shfl_xor(q, off);
    }
    float mu = s * (1.0f / D_DIM);
    float var = q * (1.0f / D_DIM) - mu * mu;
    float rstd = rsqrtf(var + LN_EPS);
    float4 gv = *reinterpret_cast<const float4*>(g + lane * 4);
    float4 bv = *reinterpret_cast<const float4*>(b + lane * 4);
    ushort4 o = make_ushort4(f2bf((xv.x - mu) * rstd * gv.x + bv.x),
                             f2bf((xv.y - mu) * rstd * gv.y + bv.y),
                             f2bf((xv.z - mu) * rstd * gv.z + bv.z),
                             f2bf((xv.w - mu) * rstd * gv.w + bv.w));
    *reinterpret_cast<ushort4*>(out + base) = o;
}

// ---------------------------------------------------------------------------
// Weight conversion fp32 -> bf16 (5 x 256x256)
// ---------------------------------------------------------------------------
__global__ __launch_bounds__(256) void wconv(const float* __restrict__ w0, const float* __restrict__ w1,
                                             const float* __restrict__ w2, const float* __restrict__ w3,
                                             const float* __restrict__ w4, ushort* __restrict__ dst) {
    const float* s;
    switch (blockIdx.y) {
        case 0: s = w0; break;
        case 1: s = w1; break;
        case 2: s = w2; break;
        case 3: s = w3; break;
        default: s = w4; break;
    }
    int idx = (blockIdx.x * 256 + threadIdx.x) * 4;
    float4 v = *reinterpret_cast<const float4*>(s + idx);
    ushort4 o = make_ushort4(f2bf(v.x), f2bf(v.y), f2bf(v.z), f2bf(v.w));
    *reinterpret_cast<ushort4*>(dst + (size_t)blockIdx.y * 65536 + idx) = o;
}

// ---------------------------------------------------------------------------
// bf16 MFMA GEMM, m97-style global_load_lds staging (linear LDS dest +
// inverse-swizzled global source, rule #21), single-buffered, 2 barriers/step.
// BM=BN=128, BK=64, 256 thr (4 waves, 64x64 out each).
// M_QKV: fused Q/K/V projection. Grid (512, 6): y>>1 selects W (wq/wk/wv,
//   contiguous) and output (qb/kb/vtb, contiguous 16M ushorts apart).
//   A is t-major (r' = t*S + s). Q epilogue pre-scales by SCQ (attn exp2 fold).
//   V epilogue stores pi-permuted s (lane-local PV A-frag in attention).
// M_H / M_FFN2: FFN layers, A row-major, grid (512, 2).
// ---------------------------------------------------------------------------
enum { M_QKV = 0, M_H = 1, M_FFN2 = 2 };

template <int MODE>
__global__ __launch_bounds__(256) void gemm_m97(const ushort* __restrict__ A,
                                                const ushort* __restrict__ Wall,
                                                const float* __restrict__ bias,
                                                const float* __restrict__ res,
                                                void* __restrict__ outp) {
    __shared__ uint4 As[1024];   // 128 rows x 8 chunks of 16B
    __shared__ uint4 Bs[1024];
    const int tid = threadIdx.x;
    const int lane = tid & 63;
    const int wid = tid >> 6;
    const int y = blockIdx.y;
    const int wm = (wid >> 1) * 64;
    const int wn = (wid & 1) * 64;

    constexpr bool QKV = (MODE == M_QKV);
    const int tblk = blockIdx.x >> 2;          // QKV: fixed t per block
    const int s0 = (blockIdx.x & 3) * 128;     // QKV: s-panel
    const int m0 = blockIdx.x * 128;

    const ushort* Abase = QKV ? A + ((size_t)s0 * T_DIM + tblk) * D_DIM
                              : A + (size_t)m0 * D_DIM;
    const size_t Ast = QKV ? (size_t)T_DIM * D_DIM : (size_t)D_DIM;
    const int n0 = QKV ? (y & 1) * 128 : y * 128;
    const ushort* Wbase = (QKV ? Wall + (size_t)(y >> 1) * 65536 : Wall) + (size_t)n0 * D_DIM;

    f32x4 acc[4][4];
#pragma unroll
    for (int mi = 0; mi < 4; ++mi)
#pragma unroll
        for (int ni = 0; ni < 4; ++ni) acc[mi][ni] = (f32x4){0.f, 0.f, 0.f, 0.f};

    const int srow = tid >> 3;   // 0..31 per iter-block
    const int sc = tid & 7;

    for (int ks = 0; ks < 4; ++ks) {
        const int k0 = ks * 64;
#pragma unroll
        for (int it = 0; it < 4; ++it) {
            int row = it * 32 + srow;
            int c = sc ^ (row & 7);
            __builtin_amdgcn_global_load_lds(
                (const AS1 void*)(Abase + (size_t)row * Ast + k0 + c * 8),
                (AS3 void*)&As[it * 256 + wid * 64], 16, 0, 0);
            __builtin_amdgcn_global_load_lds(
                (const AS1 void*)(Wbase + (size_t)row * D_DIM + k0 + c * 8),
                (AS3 void*)&Bs[it * 256 + wid * 64], 16, 0, 0);
        }
        __syncthreads();   // drain vmcnt: tile resident
#pragma unroll
        for (int kk = 0; kk < 2; ++kk) {
            short8 af[4], bf[4];
#pragma unroll
            for (int mi = 0; mi < 4; ++mi) {
                int row = wm + mi * 16 + (lane & 15);
                int c = kk * 4 + (lane >> 4);
                af[mi] = *reinterpret_cast<const short8*>(&As[row * 8 + (c ^ (row & 7))]);
            }
#pragma unroll
            for (int ni = 0; ni < 4; ++ni) {
                int row = wn + ni * 16 + (lane & 15);
                int c = kk * 4 + (lane >> 4);
                bf[ni] = *reinterpret_cast<const short8*>(&Bs[row * 8 + (c ^ (row & 7))]);
            }
#pragma unroll
            for (int mi = 0; mi < 4; ++mi)
#pragma unroll
                for (int ni = 0; ni < 4; ++ni)
                    acc[mi][ni] = __builtin_amdgcn_mfma_f32_16x16x32_bf16(af[mi], bf[ni], acc[mi][ni], 0, 0, 0);
        }
        __syncthreads();   // all reads done before next stage overwrites
    }

    // Epilogue. D layout: row=(lane>>4)*4+r, col=lane&15 (m89).
    if (MODE == M_QKV) {
        ushort* outb = (ushort*)outp + (size_t)(y >> 1) * 16777216;
        const bool isV = (y >= 4);
        const float scale = (y < 2) ? SCQ : 1.0f;
#pragma unroll
        for (int mi = 0; mi < 4; ++mi) {
#pragma unroll
            for (int ni = 0; ni < 4; ++ni) {
                int gn = n0 + wn + ni * 16 + (lane & 15);
                if (isV) {
                    // pi^-1(s): bits[4:3]=s[3:2], bit[2]=s[4]; bits 1:0 kept
                    int s = s0 + wm + mi * 16 + (lane >> 4) * 4;
                    int p = (s & ~28) | ((s & 12) << 1) | ((s & 16) >> 2);
                    ushort4 o = make_ushort4(f2bf(acc[mi][ni][0]), f2bf(acc[mi][ni][1]),
                                             f2bf(acc[mi][ni][2]), f2bf(acc[mi][ni][3]));
                    *reinterpret_cast<ushort4*>(
                        &outb[((size_t)tblk * D_DIM + gn) * S_DIM + p]) = o;
                } else {
#pragma unroll
                    for (int r = 0; r < 4; ++r) {
                        int s = s0 + wm + mi * 16 + (lane >> 4) * 4 + r;
                        outb[(size_t)tblk * (S_DIM * D_DIM) + (size_t)s * D_DIM + gn] =
                            f2bf(acc[mi][ni][r] * scale);
                    }
                }
            }
        }
    } else {
#pragma unroll
        for (int mi = 0; mi < 4; ++mi) {
#pragma unroll
            for (int ni = 0; ni < 4; ++ni) {
                int gn = n0 + wn + ni * 16 + (lane & 15);
#pragma unroll
                for (int r = 0; r < 4; ++r) {
                    int gm = m0 + wm + mi * 16 + (lane >> 4) * 4 + r;
                    float v = acc[mi][ni][r];
                    if (MODE == M_H) {
                        v += bias[gn];
                        v = fmaxf(v, 0.f);
                        ((ushort*)outp)[(size_t)gm * D_DIM + gn] = f2bf(v);
                    } else {
                        v += bias[gn] + res[(size_t)gm * D_DIM + gn];
                        ((float*)outp)[(size_t)gm * D_DIM + gn] = v;
                    }
                }
            }
        }
    }
}

// ---------------------------------------------------------------------------
// MFMA flash attention, fully in-register softmax (round-10 structure:
// RUNTIME jt loop — full unroll bloated VGPR 52->92 and cost 29% occupancy).
// Grid (x=t, y=i-chunk, z=h): all 32 blocks of one t share an XCD.
// Q pre-scaled by SCQ in projection -> exp2f(sacc) directly.
// PV A-frag lane-local via pi-permuted V^T storage. K/V double-buffered via
// global_load_lds (linear dest + inverse-swizzled global source, rule #21).
// ---------------------------------------------------------------------------
__global__ __launch_bounds__(256) void attn_mfma(const ushort* __restrict__ qb,
                                                 const ushort* __restrict__ kb,
                                                 const ushort* __restrict__ vtb,
                                                 const float* __restrict__ x,
                                                 float* __restrict__ xt) {
    __shared__ uint4 Ks[2][512];
    __shared__ uint4 Vs[2][512];
    const int tid = threadIdx.x;
    const int lane = tid & 63;
    const int wid = tid >> 6;
    const int t = blockIdx.x;
    const int h = blockIdx.z;
    const int i0 = blockIdx.y * 64 + wid * 16;

    short8 qf[2];
    {
        const ushort* qrow = qb + ((size_t)t * S_DIM + i0 + (lane & 15)) * D_DIM + h * HD;
#pragma unroll
        for (int kk = 0; kk < 2; ++kk)
            qf[kk] = *reinterpret_cast<const short8*>(qrow + kk * 32 + (lane >> 4) * 8);
    }

    f32x4 oacc[4];
#pragma unroll
    for (int dt = 0; dt < 4; ++dt) oacc[dt] = (f32x4){0.f, 0.f, 0.f, 0.f};
    float psl = 0.f;

    const ushort* kbase = kb + (size_t)t * (S_DIM * D_DIM) + h * HD;
    const ushort* vbase = vtb + ((size_t)t * D_DIM + h * HD) * S_DIM;

#define STAGE(buf, j0)                                                                      \
    {                                                                                       \
        _Pragma("unroll") for (int it = 0; it < 2; ++it) {                                  \
            int slot = wid * 128 + it * 64 + lane;                                          \
            int row = slot >> 3;                                                            \
            int c = (slot & 7) ^ (row & 7);                                                 \
            __builtin_amdgcn_global_load_lds(                                               \
                (const AS1 void*)(kbase + (size_t)((j0) + row) * D_DIM + c * 8),            \
                (AS3 void*)&Ks[buf][wid * 128 + it * 64], 16, 0, 0);                        \
            __builtin_amdgcn_global_load_lds(                                               \
                (const AS1 void*)(vbase + (size_t)row * S_DIM + (j0) + c * 8),              \
                (AS3 void*)&Vs[buf][wid * 128 + it * 64], 16, 0, 0);                        \
        }                                                                                   \
    }

    STAGE(0, 0)
    __syncthreads();
    int cur = 0;

    for (int jt = 0; jt < 8; ++jt) {
        if (jt < 7) STAGE(cur ^ 1, (jt + 1) * 64)

        f32x4 sacc[4];
#pragma unroll
        for (int ct = 0; ct < 4; ++ct) sacc[ct] = (f32x4){0.f, 0.f, 0.f, 0.f};
#pragma unroll
        for (int kk = 0; kk < 2; ++kk) {
#pragma unroll
            for (int ct = 0; ct < 4; ++ct) {
                int row = ct * 16 + (lane & 15);
                int c = kk * 4 + (lane >> 4);
                short8 kf = *reinterpret_cast<const short8*>(&Ks[cur][row * 8 + (c ^ (row & 7))]);
                sacc[ct] = __builtin_amdgcn_mfma_f32_16x16x32_bf16(kf, qf[kk], sacc[ct], 0, 0, 0);
            }
        }

        // P = exp2(S) (Q pre-scaled); pack pairs bf16x2, all lane-local
        uint pk[4][2];
#pragma unroll
        for (int ct = 0; ct < 4; ++ct) {
            float p0 = exp2f(sacc[ct][0]);
            float p1 = exp2f(sacc[ct][1]);
            float p2 = exp2f(sacc[ct][2]);
            float p3 = exp2f(sacc[ct][3]);
            psl += (p0 + p1) + (p2 + p3);
            pk[ct][0] = cvtpk(p0, p1);
            pk[ct][1] = cvtpk(p2, p3);
        }

        // O += P V : A-frag lane-local under pi (V^T pre-permuted)
#pragma unroll
        for (int jh = 0; jh < 2; ++jh) {
            int4 pd;
            pd.x = (int)pk[2 * jh][0];
            pd.y = (int)pk[2 * jh][1];
            pd.z = (int)pk[2 * jh + 1][0];
            pd.w = (int)pk[2 * jh + 1][1];
            short8 pf = *reinterpret_cast<short8*>(&pd);
            int c = jh * 4 + (lane >> 4);
#pragma unroll
            for (int dt = 0; dt < 4; ++dt) {
                int row = dt * 16 + (lane & 15);
                short8 vf = *reinterpret_cast<const short8*>(&Vs[cur][row * 8 + (c ^ (row & 7))]);
                oacc[dt] = __builtin_amdgcn_mfma_f32_16x16x32_bf16(pf, vf, oacc[dt], 0, 0, 0);
            }
        }

        if (jt < 7) {
            __syncthreads();
            cur ^= 1;
        }
    }
#undef STAGE

    // Row sums: lanes {l, l^16, l^32, l^48} share row i=lane&15
    psl += __shfl_xor(psl, 16);
    psl += __shfl_xor(psl, 32);
    float inv = 1.0f / psl;
    float invr[4];
#pragma unroll
    for (int r = 0; r < 4; ++r)
        invr[r] = __int_as_float(__builtin_amdgcn_ds_bpermute(
            (((lane >> 4) * 4 + r) << 2), __float_as_int(inv)));

#pragma unroll
    for (int dt = 0; dt < 4; ++dt) {
#pragma unroll
        for (int r = 0; r < 4; ++r) {
            int srow = i0 + (lane >> 4) * 4 + r;
            size_t oidx = (size_t)srow * (T_DIM * D_DIM) + (size_t)t * D_DIM + h * HD + dt * 16 + (lane & 15);
            xt[oidx] = x[oidx] + oacc[dt][r] * invr[r];
        }
    }
}

// ---------------------------------------------------------------------------
extern "C" void kernel_launch(void* const* d_in, const int* in_sizes, int n_in,
                              void* d_out, int out_size, void* d_ws, size_t ws_size,
                              hipStream_t stream) {
    const float* x  = (const float*)d_in[0];
    const float* wq = (const float*)d_in[1];
    const float* wk = (const float*)d_in[2];
    const float* wv = (const float*)d_in[3];
    const float* g1 = (const float*)d_in[4];
    const float* be1 = (const float*)d_in[5];
    const float* g2 = (const float*)d_in[6];
    const float* be2 = (const float*)d_in[7];
    const float* w1 = (const float*)d_in[8];
    const float* b1 = (const float*)d_in[9];
    const float* w2 = (const float*)d_in[10];
    const float* b2 = (const float*)d_in[11];
    float* out = (float*)d_out;

    char* ws = (char*)d_ws;
    const size_t MB = 1024ull * 1024;
    ushort* xnb = (ushort*)ws;                // 32 MB: LN1 out, later LN2 out
    ushort* qb  = (ushort*)(ws + 32 * MB);    // 32 MB: Q [T,S,D] (pre-scaled); later FFN hidden
    ushort* kb  = (ushort*)(ws + 64 * MB);    // 32 MB: K [T,S,D]
    ushort* vtb = (ushort*)(ws + 96 * MB);    // 32 MB: V^T [T,D,S] (pi-permuted s)
    ushort* wb  = (ushort*)(ws + 128 * MB);   // 5 x 64K bf16 weights (wq,wk,wv,w1,w2)
    ushort* w1b = wb + 3 * 65536;
    ushort* w2b = wb + 4 * 65536;
    ushort* hb  = qb;

    wconv<<<dim3(64, 5), 256, 0, stream>>>(wq, wk, wv, w1, w2, wb);
    ln_bf16<<<NROWS / 4, 256, 0, stream>>>(x, g1, be1, xnb);
    gemm_m97<M_QKV><<<dim3(512, 6), 256, 0, stream>>>(xnb, wb, nullptr, nullptr, qb);
    attn_mfma<<<dim3(T_DIM, S_DIM / 64, 4), 256, 0, stream>>>(qb, kb, vtb, x, out);
    ln_bf16<<<NROWS / 4, 256, 0, stream>>>(out, g2, be2, xnb);
    gemm_m97<M_H><<<dim3(512, 2), 256, 0, stream>>>(xnb, w1b, b1, nullptr, hb);
    gemm_m97<M_FFN2><<<dim3(512, 2), 256, 0, stream>>>(hb, w2b, b2, out, out);
}